// Round 1
// baseline (327.959 us; speedup 1.0000x reference)
//
#include <hip/hip_runtime.h>
#include <math.h>

#define B_ 4
#define N_ 4096
#define D_ 1024
#define H_ 16
#define HD_ 64
#define FB_ 2049
#define M2_ 2048

__device__ __forceinline__ float2 cmul(float2 a, float2 b) {
    return make_float2(a.x*b.x - a.y*b.y, a.x*b.y + a.y*b.x);
}

// tanh-approx GELU (jax.nn.gelu default), m >= 0 here
__device__ __forceinline__ float gelu_t(float m) {
    float u = 0.7978845608028654f * (m + 0.044715f * m * m * m);
    float e = __expf(-2.0f * u);           // u>=0 -> e in (0,1], no overflow
    float th = (1.0f - e) / (1.0f + e);
    return 0.5f * m * (1.0f + th);
}

__device__ __forceinline__ float2 cact(float2 z) {
    float m = sqrtf(z.x*z.x + z.y*z.y);
    float s = gelu_t(m) / (m + 1e-6f);
    return make_float2(z.x*s, z.y*s);
}

// ---------------- K1: per-row LayerNorm stats ----------------
__global__ __launch_bounds__(256) void k_rowstats(const float* __restrict__ x,
                                                  float2* __restrict__ stats) {
    int row = blockIdx.x;                      // B*N rows
    const float4* xr = (const float4*)(x + (size_t)row * D_);
    float4 v = xr[threadIdx.x];                // 256 float4 = 1024 floats
    float s = v.x + v.y + v.z + v.w;
    float q = v.x*v.x + v.y*v.y + v.z*v.z + v.w*v.w;
    for (int o = 32; o; o >>= 1) { s += __shfl_down(s, o); q += __shfl_down(q, o); }
    __shared__ float ls[4], lq[4];
    int lane = threadIdx.x & 63, w = threadIdx.x >> 6;
    if (!lane) { ls[w] = s; lq[w] = q; }
    __syncthreads();
    if (threadIdx.x == 0) {
        s = ls[0] + ls[1] + ls[2] + ls[3];
        q = lq[0] + lq[1] + lq[2] + lq[3];
        float mu = s * (1.0f / D_);
        float var = q * (1.0f / D_) - mu * mu;
        stats[row] = make_float2(mu, rsqrtf(var + 1e-5f));
    }
}

// ---------------- K2: LN apply + transpose to (b,h,d,n) + context partials ----------------
__global__ __launch_bounds__(256) void k_transnorm(const float* __restrict__ x,
                                                   const float2* __restrict__ stats,
                                                   const float* __restrict__ lnw,
                                                   const float* __restrict__ lnb,
                                                   float* __restrict__ xt,
                                                   float* __restrict__ cpart) {
    __shared__ float tile[64 * 65];
    __shared__ float gsum[256];
    int bid = blockIdx.x;                      // B * 64 * 16 = 4096
    int b = bid >> 10;
    int rem = bid & 1023;
    int nt = rem >> 4;                         // 64 n-tiles
    int dt = rem & 15;                         // 16 d-tiles (= head)
    int n0 = nt << 6, d0 = dt << 6;
    int tx = threadIdx.x & 63;
    int ty = threadIdx.x >> 6;
    float wv = lnw[d0 + tx], bv = lnb[d0 + tx];
    const float* xb = x + ((size_t)b * N_ + n0) * D_ + d0 + tx;
    for (int r = 0; r < 16; r++) {
        int row = ty + 4 * r;
        float2 st = stats[(size_t)b * N_ + n0 + row];
        float val = (xb[(size_t)row * D_] - st.x) * st.y * wv + bv;
        tile[row * 65 + tx] = val;
    }
    __syncthreads();
    // per-d partial sums over the 64 rows of this tile (deterministic)
    float s = 0.f;
    for (int r = 0; r < 16; r++) s += tile[(ty * 16 + r) * 65 + tx];
    gsum[ty * 64 + tx] = s;
    // transposed write: xt[b][h=dt][dloc][n]
    float* xtb = xt + (((size_t)b * H_ + dt) * HD_) * (size_t)N_ + n0;
    for (int r = 0; r < 16; r++) {
        int dloc = ty + 4 * r;
        xtb[(size_t)dloc * N_ + tx] = tile[tx * 65 + dloc];
    }
    __syncthreads();
    if (threadIdx.x < 64) {
        float cs = gsum[threadIdx.x] + gsum[64 + threadIdx.x] +
                   gsum[128 + threadIdx.x] + gsum[192 + threadIdx.x];
        cpart[((size_t)b * 64 + nt) * D_ + d0 + threadIdx.x] = cs;
    }
}

// ---------------- K3: finalize context ----------------
__global__ __launch_bounds__(256) void k_ctx(const float* __restrict__ cpart,
                                             float* __restrict__ ctx) {
    int id = blockIdx.x * 256 + threadIdx.x;   // 4096 = B*D
    int b = id >> 10, d = id & 1023;
    float s = 0.f;
    const float* p = cpart + (size_t)b * 64 * D_ + d;
    for (int g = 0; g < 64; g++) s += p[g * D_];
    ctx[id] = s * (1.0f / N_);
}

// ---------------- K4/K5: dense 1024x1024 layer + ReLU (M=4) ----------------
__global__ __launch_bounds__(256) void k_mlp(const float* __restrict__ in,
                                             const float* __restrict__ w,
                                             const float* __restrict__ bias,
                                             float* __restrict__ out) {
    __shared__ float li[4 * 1024];
    for (int i = threadIdx.x; i < 4096; i += 256) li[i] = in[i];
    __syncthreads();
    int col = blockIdx.x * 64 + (threadIdx.x & 63);   // 16 blocks * 64
    int b = threadIdx.x >> 6;
    float acc = 0.f;
    const float* wp = w + col;
    const float* ip = li + b * 1024;
    for (int k = 0; k < 1024; k++) acc = fmaf(ip[k], wp[(size_t)k * 1024], acc);
    acc += bias[col];
    out[b * 1024 + col] = fmaxf(acc, 0.0f);
}

// ---------------- K6: adapt head (w2) + effective filter/bias ----------------
__global__ __launch_bounds__(256) void k_adapt(const float* __restrict__ h2,
                                               const float* __restrict__ w2,
                                               const float* __restrict__ b2,
                                               const float* __restrict__ bfilt,
                                               const float* __restrict__ bbias,
                                               float2* __restrict__ eff) {
    __shared__ float lh[4096];
    __shared__ float accs[256][4];
    for (int i = threadIdx.x; i < 4096; i += 256) lh[i] = h2[i];
    __syncthreads();
    int j = blockIdx.x * 256 + threadIdx.x;     // 65568 columns
    float a0 = 0.f, a1 = 0.f, a2 = 0.f, a3 = 0.f;
    if (j < 65568) {
        const float* wp = w2 + j;
        for (int k = 0; k < 1024; k++) {
            float wvv = wp[(size_t)k * 65568];
            a0 = fmaf(lh[k],        wvv, a0);
            a1 = fmaf(lh[1024 + k], wvv, a1);
            a2 = fmaf(lh[2048 + k], wvv, a2);
            a3 = fmaf(lh[3072 + k], wvv, a3);
        }
        float bb = b2[j];
        a0 += bb; a1 += bb; a2 += bb; a3 += bb;
    }
    accs[threadIdx.x][0] = a0; accs[threadIdx.x][1] = a1;
    accs[threadIdx.x][2] = a2; accs[threadIdx.x][3] = a3;
    __syncthreads();
    if (!(j & 1) && j < 65568) {
        int p = j >> 1;                          // = h*2049 + k
        float bf = bfilt[p], bbs = bbias[p];
        for (int b = 0; b < 4; b++) {
            float sc = accs[threadIdx.x][b];
            float bi = accs[threadIdx.x + 1][b];
            eff[((size_t)b * H_ + (p / 2049)) * FB_ + (p % 2049)] =
                make_float2(bf * (1.0f + sc), bbs + bi);
        }
    }
}

// ---------------- K7: packed real FFT + spectral mod + activation + iFFT (in place) -------
__global__ __launch_bounds__(256) void k_fftmod(float* __restrict__ xt,
                                                const float2* __restrict__ eff) {
    __shared__ float2 bufA[2048];
    __shared__ float2 bufB[2048];
    __shared__ float2 tw[1024];                 // e^{-i*2*pi*j/2048}
    int t = threadIdx.x;
    int sig = blockIdx.x;                       // B*H*HD = 4096 signals
    int b = sig >> 10;
    int hd = sig & 1023;
    int h = hd >> 6;
    const float2* ef = eff + ((size_t)b * H_ + h) * FB_;
    float* xp = xt + (size_t)sig * N_;

    for (int ji = t; ji < 1024; ji += 256) {
        float sv, cv;
        sincosf(-(float)M_PI * (float)ji * (1.0f / 1024.0f), &sv, &cv);
        tw[ji] = make_float2(cv, sv);
    }
    for (int i = t; i < 1024; i += 256) {       // pack reals as complex
        float4 v = ((const float4*)xp)[i];
        bufA[2 * i]     = make_float2(v.x, v.y);
        bufA[2 * i + 1] = make_float2(v.z, v.w);
    }
    __syncthreads();

    // forward Stockham radix-2, 11 stages, natural order out
    float2 *src = bufA, *dst = bufB;
    for (int m = 1; m <= 1024; m <<= 1) {
        for (int idx = t; idx < 1024; idx += 256) {
            int k = idx & (m - 1);
            float2 c0 = src[idx], c1 = src[idx + 1024];
            float2 w = tw[idx & ~(m - 1)];
            float2 sum = make_float2(c0.x + c1.x, c0.y + c1.y);
            float2 dif = make_float2(c0.x - c1.x, c0.y - c1.y);
            int d0 = 2 * idx - k;
            dst[d0] = sum;
            dst[d0 + m] = cmul(w, dif);
        }
        __syncthreads();
        float2* tmp = src; src = dst; dst = tmp;
    }
    // src = packed spectrum Z[0..2047]; unpack pairs, modify, activate, repack into dst
    for (int k = t + 1; k <= 1024; k += 256) {
        if (k == 1024) {
            float2 Z = src[1024];
            float2 fb = ef[1024];
            float2 Y = make_float2(Z.x * fb.x + fb.y, -Z.y * fb.x);  // X = conj(Z)
            Y = cact(Y);
            dst[1024] = make_float2(Y.x, -Y.y);
        } else {
            float2 Zk = src[k], Zq = src[2048 - k];
            float2 E = make_float2(0.5f * (Zk.x + Zq.x), 0.5f * (Zk.y - Zq.y));
            float2 O = make_float2(0.5f * (Zk.y + Zq.y), 0.5f * (Zq.x - Zk.x));
            float sv, cv;
            sincosf(-(float)M_PI * (float)k * (1.0f / 2048.0f), &sv, &cv);
            float2 W = make_float2(cv, sv);     // e^{-2 pi i k / 4096}
            float2 WO = cmul(W, O);
            float2 Xk = make_float2(E.x + WO.x, E.y + WO.y);
            float2 Xq = make_float2(E.x - WO.x, -(E.y - WO.y));      // conj(E - WO)
            float2 fbk = ef[k], fbq = ef[2048 - k];
            float2 Yk = make_float2(Xk.x * fbk.x + fbk.y, Xk.y * fbk.x);
            float2 Yq = make_float2(Xq.x * fbq.x + fbq.y, Xq.y * fbq.x);
            Yk = cact(Yk); Yq = cact(Yq);
            float2 E2 = make_float2(0.5f * (Yk.x + Yq.x), 0.5f * (Yk.y - Yq.y));
            float2 A2 = make_float2(Yk.x - Yq.x, Yk.y + Yq.y);
            float2 Wc = make_float2(W.x, -W.y);
            float2 O2 = cmul(Wc, A2);
            O2.x *= 0.5f; O2.y *= 0.5f;
            dst[k]        = make_float2(E2.x - O2.y, E2.y + O2.x);
            dst[2048 - k] = make_float2(E2.x + O2.y, O2.x - E2.y);
        }
    }
    if (t == 0) {                                // k=0 and Nyquist (both real)
        float2 Z0 = src[0];
        float X0 = Z0.x + Z0.y, XN = Z0.x - Z0.y;
        float2 f0 = ef[0], fN = ef[2048];
        float Y0 = X0 * f0.x + f0.y;
        float YN = XN * fN.x + fN.y;
        float m0 = fabsf(Y0); Y0 *= gelu_t(m0) / (m0 + 1e-6f);
        float mN = fabsf(YN); YN *= gelu_t(mN) / (mN + 1e-6f);
        dst[0] = make_float2(0.5f * (Y0 + YN), 0.5f * (Y0 - YN));
    }
    __syncthreads();
    { float2* tmp = src; src = dst; dst = tmp; } // Z' now in src

    // inverse Stockham (conjugate twiddles), scale 1/2048 on store
    for (int m = 1; m <= 1024; m <<= 1) {
        for (int idx = t; idx < 1024; idx += 256) {
            int k = idx & (m - 1);
            float2 c0 = src[idx], c1 = src[idx + 1024];
            float2 w = tw[idx & ~(m - 1)];
            w.y = -w.y;
            float2 sum = make_float2(c0.x + c1.x, c0.y + c1.y);
            float2 dif = make_float2(c0.x - c1.x, c0.y - c1.y);
            int d0 = 2 * idx - k;
            dst[d0] = sum;
            dst[d0 + m] = cmul(w, dif);
        }
        __syncthreads();
        float2* tmp = src; src = dst; dst = tmp;
    }
    const float sc = 1.0f / 2048.0f;
    for (int i = t; i < 1024; i += 256) {
        float2 z0 = src[2 * i], z1 = src[2 * i + 1];
        ((float4*)xp)[i] = make_float4(z0.x * sc, z0.y * sc, z1.x * sc, z1.y * sc);
    }
}

// ---------------- K8: transpose back to (B,N,D) ----------------
__global__ __launch_bounds__(256) void k_transout(const float* __restrict__ xt,
                                                  float* __restrict__ out) {
    __shared__ float tile[64 * 65];
    int bid = blockIdx.x;
    int b = bid >> 10;
    int rem = bid & 1023;
    int nt = rem >> 4;
    int dt = rem & 15;
    int n0 = nt << 6;
    int tx = threadIdx.x & 63, ty = threadIdx.x >> 6;
    const float* xtb = xt + (((size_t)b * H_ + dt) * HD_) * (size_t)N_ + n0;
    for (int r = 0; r < 16; r++) {
        int dloc = ty + 4 * r;
        tile[dloc * 65 + tx] = xtb[(size_t)dloc * N_ + tx];
    }
    __syncthreads();
    float* ob = out + ((size_t)b * N_ + n0) * D_ + dt * HD_;
    for (int r = 0; r < 16; r++) {
        int nn = ty + 4 * r;
        ob[(size_t)nn * D_ + tx] = tile[tx * 65 + nn];
    }
}

extern "C" void kernel_launch(void* const* d_in, const int* in_sizes, int n_in,
                              void* d_out, int out_size, void* d_ws, size_t ws_size,
                              hipStream_t stream) {
    const float* x     = (const float*)d_in[0];
    const float* lnw   = (const float*)d_in[1];
    const float* lnb   = (const float*)d_in[2];
    const float* bfilt = (const float*)d_in[3];
    const float* bbias = (const float*)d_in[4];
    const float* w0    = (const float*)d_in[5];
    const float* b0    = (const float*)d_in[6];
    const float* w1    = (const float*)d_in[7];
    const float* b1    = (const float*)d_in[8];
    const float* w2    = (const float*)d_in[9];
    const float* b2    = (const float*)d_in[10];

    float* ws = (float*)d_ws;
    float*  xt    = ws;                                   // 16777216 floats (64 MB)
    float2* stats = (float2*)(ws + 16777216);             // 16384 float2
    float*  cpart = ws + 16777216 + 32768;                // 262144
    float*  ctx   = cpart + 262144;                       // 4096
    float*  h1    = ctx + 4096;                           // 4096
    float*  h2    = h1 + 4096;                            // 4096
    float2* eff   = (float2*)(h2 + 4096);                 // 131136 float2
    float*  out   = (float*)d_out;

    k_rowstats <<<16384, 256, 0, stream>>>(x, stats);
    k_transnorm<<<4096,  256, 0, stream>>>(x, stats, lnw, lnb, xt, cpart);
    k_ctx      <<<16,    256, 0, stream>>>(cpart, ctx);
    k_mlp      <<<16,    256, 0, stream>>>(ctx, w0, b0, h1);
    k_mlp      <<<16,    256, 0, stream>>>(h1, w1, b1, h2);
    k_adapt    <<<257,   256, 0, stream>>>(h2, w2, b2, bfilt, bbias, eff);
    k_fftmod   <<<4096,  256, 0, stream>>>(xt, eff);
    k_transout <<<4096,  256, 0, stream>>>(xt, out);
}

// Round 2
// 247.097 us; speedup vs baseline: 1.3272x; 1.3272x over previous
//
#include <hip/hip_runtime.h>
#include <math.h>

#define B_ 4
#define N_ 4096
#define D_ 1024
#define H_ 16
#define HD_ 64
#define FB_ 2049

__device__ __forceinline__ float2 cmul(float2 a, float2 b) {
    return make_float2(a.x*b.x - a.y*b.y, a.x*b.y + a.y*b.x);
}
__device__ __forceinline__ float2 cadd(float2 a, float2 b){return make_float2(a.x+b.x,a.y+b.y);}
__device__ __forceinline__ float2 csub(float2 a, float2 b){return make_float2(a.x-b.x,a.y-b.y);}
__device__ __forceinline__ float2 cconj(float2 a){return make_float2(a.x,-a.y);}

// tanh-approx GELU (jax.nn.gelu default), m >= 0 here
__device__ __forceinline__ float gelu_t(float m) {
    float u = 0.7978845608028654f * (m + 0.044715f * m * m * m);
    float e = __expf(-2.0f * u);
    float th = (1.0f - e) / (1.0f + e);
    return 0.5f * m * (1.0f + th);
}
__device__ __forceinline__ float2 cact(float2 z) {
    float m = sqrtf(z.x*z.x + z.y*z.y);
    float s = gelu_t(m) / (m + 1e-6f);
    return make_float2(z.x*s, z.y*s);
}

// skewed LDS index: breaks all power-of-2 stride bank conflicts to <=2-way
#define IX(e) ((e) + ((e) >> 4))

// ---------------- K1: per-row LayerNorm stats ----------------
__global__ __launch_bounds__(256) void k_rowstats(const float* __restrict__ x,
                                                  float2* __restrict__ stats) {
    int row = blockIdx.x;                      // B*N rows
    const float4* xr = (const float4*)(x + (size_t)row * D_);
    float4 v = xr[threadIdx.x];
    float s = v.x + v.y + v.z + v.w;
    float q = v.x*v.x + v.y*v.y + v.z*v.z + v.w*v.w;
    for (int o = 32; o; o >>= 1) { s += __shfl_down(s, o); q += __shfl_down(q, o); }
    __shared__ float ls[4], lq[4];
    int lane = threadIdx.x & 63, w = threadIdx.x >> 6;
    if (!lane) { ls[w] = s; lq[w] = q; }
    __syncthreads();
    if (threadIdx.x == 0) {
        s = ls[0] + ls[1] + ls[2] + ls[3];
        q = lq[0] + lq[1] + lq[2] + lq[3];
        float mu = s * (1.0f / D_);
        float var = q * (1.0f / D_) - mu * mu;
        stats[row] = make_float2(mu, rsqrtf(var + 1e-5f));
    }
}

// ---------------- K2: LN apply + transpose to (b,h,d,n) + context partials ----------------
__global__ __launch_bounds__(256) void k_transnorm(const float* __restrict__ x,
                                                   const float2* __restrict__ stats,
                                                   const float* __restrict__ lnw,
                                                   const float* __restrict__ lnb,
                                                   float* __restrict__ xt,
                                                   float* __restrict__ cpart) {
    __shared__ float tile[64 * 65];
    __shared__ float gsum[256];
    int bid = blockIdx.x;                      // B * 64 * 16 = 4096
    int b = bid >> 10;
    int rem = bid & 1023;
    int nt = rem >> 4;
    int dt = rem & 15;
    int n0 = nt << 6, d0 = dt << 6;
    int tx = threadIdx.x & 63;
    int ty = threadIdx.x >> 6;
    float wv = lnw[d0 + tx], bv = lnb[d0 + tx];
    const float* xb = x + ((size_t)b * N_ + n0) * D_ + d0 + tx;
    for (int r = 0; r < 16; r++) {
        int row = ty + 4 * r;
        float2 st = stats[(size_t)b * N_ + n0 + row];
        float val = (xb[(size_t)row * D_] - st.x) * st.y * wv + bv;
        tile[row * 65 + tx] = val;
    }
    __syncthreads();
    float s = 0.f;
    for (int r = 0; r < 16; r++) s += tile[(ty * 16 + r) * 65 + tx];
    gsum[ty * 64 + tx] = s;
    float* xtb = xt + (((size_t)b * H_ + dt) * HD_) * (size_t)N_ + n0;
    for (int r = 0; r < 16; r++) {
        int dloc = ty + 4 * r;
        xtb[(size_t)dloc * N_ + tx] = tile[tx * 65 + dloc];
    }
    __syncthreads();
    if (threadIdx.x < 64) {
        float cs = gsum[threadIdx.x] + gsum[64 + threadIdx.x] +
                   gsum[128 + threadIdx.x] + gsum[192 + threadIdx.x];
        cpart[((size_t)b * 64 + nt) * D_ + d0 + threadIdx.x] = cs;
    }
}

// ---------------- K3: finalize context ----------------
__global__ __launch_bounds__(256) void k_ctx(const float* __restrict__ cpart,
                                             float* __restrict__ ctx) {
    int id = blockIdx.x * 256 + threadIdx.x;   // 4096 = B*D
    int b = id >> 10, d = id & 1023;
    float s = 0.f;
    const float* p = cpart + (size_t)b * 64 * D_ + d;
    #pragma unroll 8
    for (int g = 0; g < 64; g++) s += p[g * D_];
    ctx[id] = s * (1.0f / N_);
}

// ---------------- K4: layer-0 partial GEMM (in = ctx direct) ----------------
// grid (16 colgroups, 4 kslices); part[ks][b][1024]
__global__ __launch_bounds__(256) void k_mlp_part(const float* __restrict__ in,
                                                  const float* __restrict__ w,
                                                  float* __restrict__ part) {
    __shared__ float li[4 * 256];
    int ks = blockIdx.y;
    for (int i = threadIdx.x; i < 1024; i += 256) {
        int b = i >> 8, kk = i & 255;
        li[i] = in[b * 1024 + ks * 256 + kk];
    }
    __syncthreads();
    int col = blockIdx.x * 64 + (threadIdx.x & 63);
    int b = threadIdx.x >> 6;
    const float* wp = w + (size_t)(ks * 256) * 1024 + col;
    const float* ip = li + b * 256;
    float acc = 0.f;
    #pragma unroll 8
    for (int k = 0; k < 256; k++) acc = fmaf(ip[k], wp[(size_t)k * 1024], acc);
    part[((size_t)ks * 4 + b) * 1024 + col] = acc;
}

// ---------------- K5: layer-1 partial GEMM (in = layer-0 partials + bias + relu) --------
__global__ __launch_bounds__(256) void k_mlp_part2(const float* __restrict__ part,
                                                   const float* __restrict__ bias,
                                                   const float* __restrict__ w,
                                                   float* __restrict__ part2) {
    __shared__ float li[4 * 256];
    int ks = blockIdx.y;
    for (int i = threadIdx.x; i < 1024; i += 256) {
        int b = i >> 8, kk = (i & 255) + ks * 256;
        float v = part[b * 1024 + kk] + part[4096 + b * 1024 + kk] +
                  part[8192 + b * 1024 + kk] + part[12288 + b * 1024 + kk] + bias[kk];
        li[i] = fmaxf(v, 0.f);
    }
    __syncthreads();
    int col = blockIdx.x * 64 + (threadIdx.x & 63);
    int b = threadIdx.x >> 6;
    const float* wp = w + (size_t)(ks * 256) * 1024 + col;
    const float* ip = li + b * 256;
    float acc = 0.f;
    #pragma unroll 8
    for (int k = 0; k < 256; k++) acc = fmaf(ip[k], wp[(size_t)k * 1024], acc);
    part2[((size_t)ks * 4 + b) * 1024 + col] = acc;
}

// ---------------- K6: w2 partial GEMM, float4 cols, 8 k-slices ----------------
// grid (65, 8); part3[ks][b][65568]
__global__ __launch_bounds__(256) void k_adapt_part(const float* __restrict__ part2,
                                                    const float* __restrict__ b1,
                                                    const float* __restrict__ w2,
                                                    float* __restrict__ part3) {
    __shared__ float lh[4 * 128];
    int ks = blockIdx.y;
    for (int i = threadIdx.x; i < 512; i += 256) {
        int b = i >> 7, kk = (i & 127) + ks * 128;
        float v = part2[b * 1024 + kk] + part2[4096 + b * 1024 + kk] +
                  part2[8192 + b * 1024 + kk] + part2[12288 + b * 1024 + kk] + b1[kk];
        lh[i] = fmaxf(v, 0.f);
    }
    __syncthreads();
    int j4 = blockIdx.x * 1024 + threadIdx.x * 4;
    if (j4 < 65568) {
        float a0x=0,a0y=0,a0z=0,a0w=0, a1x=0,a1y=0,a1z=0,a1w=0;
        float a2x=0,a2y=0,a2z=0,a2w=0, a3x=0,a3y=0,a3z=0,a3w=0;
        const float* wp = w2 + (size_t)(ks * 128) * 65568 + j4;
        #pragma unroll 4
        for (int k = 0; k < 128; k++) {
            float4 wv = *(const float4*)(wp + (size_t)k * 65568);
            float h0 = lh[k], h1 = lh[128 + k], h2 = lh[256 + k], h3 = lh[384 + k];
            a0x = fmaf(h0, wv.x, a0x); a0y = fmaf(h0, wv.y, a0y);
            a0z = fmaf(h0, wv.z, a0z); a0w = fmaf(h0, wv.w, a0w);
            a1x = fmaf(h1, wv.x, a1x); a1y = fmaf(h1, wv.y, a1y);
            a1z = fmaf(h1, wv.z, a1z); a1w = fmaf(h1, wv.w, a1w);
            a2x = fmaf(h2, wv.x, a2x); a2y = fmaf(h2, wv.y, a2y);
            a2z = fmaf(h2, wv.z, a2z); a2w = fmaf(h2, wv.w, a2w);
            a3x = fmaf(h3, wv.x, a3x); a3y = fmaf(h3, wv.y, a3y);
            a3z = fmaf(h3, wv.z, a3z); a3w = fmaf(h3, wv.w, a3w);
        }
        float* p3 = part3 + (size_t)ks * 4 * 65568 + j4;
        *(float4*)(p3)              = make_float4(a0x, a0y, a0z, a0w);
        *(float4*)(p3 + 65568)      = make_float4(a1x, a1y, a1z, a1w);
        *(float4*)(p3 + 2 * 65568)  = make_float4(a2x, a2y, a2z, a2w);
        *(float4*)(p3 + 3 * 65568)  = make_float4(a3x, a3y, a3z, a3w);
    }
}

// ---------------- K7: finalize adapt -> effective filter/bias ----------------
__global__ __launch_bounds__(256) void k_eff(const float* __restrict__ part3,
                                             const float* __restrict__ b2,
                                             const float* __restrict__ bfilt,
                                             const float* __restrict__ bbias,
                                             float2* __restrict__ eff) {
    int p = blockIdx.x * 256 + threadIdx.x;     // 32784 = H*FB
    if (p >= 32784) return;
    int h = p / 2049, f = p % 2049;
    float bf = bfilt[p], bb = bbias[p];
    float sc0 = b2[2 * p], bi0 = b2[2 * p + 1];
    #pragma unroll
    for (int b = 0; b < 4; b++) {
        float sc = sc0, bi = bi0;
        #pragma unroll
        for (int s = 0; s < 8; s++) {
            const float* q = part3 + ((size_t)s * 4 + b) * 65568 + 2 * p;
            sc += q[0]; bi += q[1];
        }
        eff[((size_t)b * H_ + h) * FB_ + f] = make_float2(bf * (1.0f + sc), bb + bi);
    }
}

// ---------------- K8: radix-4 packed real FFT + spectral mod + iFFT (in place) ----------
__global__ __launch_bounds__(256) void k_fftmod(float* __restrict__ xt,
                                                const float2* __restrict__ eff) {
    __shared__ float2 bufA[2176];
    __shared__ float2 bufB[2176];
    __shared__ float2 tw[1088];                 // e^{-2 pi i j/2048}, j<1024, skewed
    int t = threadIdx.x;
    int sig = blockIdx.x;                       // B*H*HD = 4096 signals
    int b = sig >> 10;
    int h = (sig & 1023) >> 6;
    const float2* ef = eff + ((size_t)b * H_ + h) * FB_;
    float* xp = xt + (size_t)sig * N_;

    #pragma unroll
    for (int ii = 0; ii < 4; ii++) {
        int ji = t + ii * 256;
        float sv, cv;
        __sincosf(-(float)M_PI * (float)ji * (1.0f / 1024.0f), &sv, &cv);
        tw[IX(ji)] = make_float2(cv, sv);
    }
    #pragma unroll
    for (int ii = 0; ii < 4; ii++) {            // pack reals as complex
        int i = t + ii * 256;
        float4 v = ((const float4*)xp)[i];
        bufA[IX(2 * i)]     = make_float2(v.x, v.y);
        bufA[IX(2 * i + 1)] = make_float2(v.z, v.w);
    }
    __syncthreads();

    float2 *src = bufA, *dst = bufB;
    // forward: 5 radix-4 stages (m = 1,4,16,64,256)
    for (int m = 1; m <= 256; m <<= 2) {
        #pragma unroll
        for (int it = 0; it < 2; it++) {
            int idx = t + it * 256;
            int km = idx & (m - 1);
            int jm = idx - km;
            float2 u0 = src[IX(idx)];
            float2 u1 = src[IX(idx + 512)];
            float2 u2 = src[IX(idx + 1024)];
            float2 u3 = src[IX(idx + 1536)];
            float2 t0 = cadd(u0, u2), t1 = csub(u0, u2);
            float2 t2 = cadd(u1, u3), t3 = csub(u1, u3);
            float2 w1 = tw[IX(jm)], w2 = tw[IX(2 * jm)];
            float2 w3 = cmul(w1, w2);
            int base = 4 * idx - 3 * km;
            dst[IX(base)]         = cadd(t0, t2);
            dst[IX(base + m)]     = cmul(w1, make_float2(t1.x + t3.y, t1.y - t3.x));
            dst[IX(base + 2*m)]   = cmul(w2, csub(t0, t2));
            dst[IX(base + 3*m)]   = cmul(w3, make_float2(t1.x - t3.y, t1.y + t3.x));
        }
        __syncthreads();
        float2* tmp = src; src = dst; dst = tmp;
    }
    // final radix-2 stage m=1024 (twiddle = 1)
    #pragma unroll
    for (int it = 0; it < 4; it++) {
        int idx = t + it * 256;
        float2 c0 = src[IX(idx)], c1 = src[IX(idx + 1024)];
        dst[IX(idx)]        = cadd(c0, c1);
        dst[IX(idx + 1024)] = csub(c0, c1);
    }
    __syncthreads();
    { float2* tmp = src; src = dst; dst = tmp; }

    // spectral unpack/modify/activate/repack
    const float2 Codd = make_float2(0.99999882345170188f, -0.0015339801862847657f); // e^{-i pi/2048}
    #pragma unroll
    for (int ii = 0; ii < 4; ii++) {
        int k = t + 1 + ii * 256;
        if (k == 1024) {
            float2 Z = src[IX(1024)];
            float2 fb = ef[1024];
            float2 Y = make_float2(Z.x * fb.x + fb.y, -Z.y * fb.x);
            Y = cact(Y);
            dst[IX(1024)] = make_float2(Y.x, -Y.y);
        } else {
            float2 Zk = src[IX(k)], Zq = src[IX(2048 - k)];
            float2 E = make_float2(0.5f * (Zk.x + Zq.x), 0.5f * (Zk.y - Zq.y));
            float2 O = make_float2(0.5f * (Zk.y + Zq.y), 0.5f * (Zq.x - Zk.x));
            float2 Wt = tw[IX(k >> 1)];
            float2 W = (k & 1) ? cmul(Codd, Wt) : Wt;   // e^{-2 pi i k/4096}
            float2 WO = cmul(W, O);
            float2 Xk = cadd(E, WO);
            float2 Xq = make_float2(E.x - WO.x, -(E.y - WO.y));
            float2 fbk = ef[k], fbq = ef[2048 - k];
            float2 Yk = make_float2(Xk.x * fbk.x + fbk.y, Xk.y * fbk.x);
            float2 Yq = make_float2(Xq.x * fbq.x + fbq.y, Xq.y * fbq.x);
            Yk = cact(Yk); Yq = cact(Yq);
            float2 E2 = make_float2(0.5f * (Yk.x + Yq.x), 0.5f * (Yk.y - Yq.y));
            float2 A2 = make_float2(Yk.x - Yq.x, Yk.y + Yq.y);
            float2 O2 = cmul(cconj(W), A2);
            O2.x *= 0.5f; O2.y *= 0.5f;
            dst[IX(k)]        = make_float2(E2.x - O2.y, E2.y + O2.x);
            dst[IX(2048 - k)] = make_float2(E2.x + O2.y, O2.x - E2.y);
        }
    }
    if (t == 0) {
        float2 Z0 = src[IX(0)];
        float X0 = Z0.x + Z0.y, XN = Z0.x - Z0.y;
        float2 f0 = ef[0], fN = ef[2048];
        float Y0 = X0 * f0.x + f0.y;
        float YN = XN * fN.x + fN.y;
        float m0 = fabsf(Y0); Y0 *= gelu_t(m0) / (m0 + 1e-6f);
        float mN = fabsf(YN); YN *= gelu_t(mN) / (mN + 1e-6f);
        dst[IX(0)] = make_float2(0.5f * (Y0 + YN), 0.5f * (Y0 - YN));
    }
    __syncthreads();
    { float2* tmp = src; src = dst; dst = tmp; }

    // inverse: 5 radix-4 stages (conjugate twiddles)
    for (int m = 1; m <= 256; m <<= 2) {
        #pragma unroll
        for (int it = 0; it < 2; it++) {
            int idx = t + it * 256;
            int km = idx & (m - 1);
            int jm = idx - km;
            float2 u0 = src[IX(idx)];
            float2 u1 = src[IX(idx + 512)];
            float2 u2 = src[IX(idx + 1024)];
            float2 u3 = src[IX(idx + 1536)];
            float2 t0 = cadd(u0, u2), t1 = csub(u0, u2);
            float2 t2 = cadd(u1, u3), t3 = csub(u1, u3);
            float2 w1 = cconj(tw[IX(jm)]), w2 = cconj(tw[IX(2 * jm)]);
            float2 w3 = cmul(w1, w2);
            int base = 4 * idx - 3 * km;
            dst[IX(base)]         = cadd(t0, t2);
            dst[IX(base + m)]     = cmul(w1, make_float2(t1.x - t3.y, t1.y + t3.x));
            dst[IX(base + 2*m)]   = cmul(w2, csub(t0, t2));
            dst[IX(base + 3*m)]   = cmul(w3, make_float2(t1.x + t3.y, t1.y - t3.x));
        }
        __syncthreads();
        float2* tmp = src; src = dst; dst = tmp;
    }
    // final radix-2 stage m=1024
    #pragma unroll
    for (int it = 0; it < 4; it++) {
        int idx = t + it * 256;
        float2 c0 = src[IX(idx)], c1 = src[IX(idx + 1024)];
        dst[IX(idx)]        = cadd(c0, c1);
        dst[IX(idx + 1024)] = csub(c0, c1);
    }
    __syncthreads();
    { float2* tmp = src; src = dst; dst = tmp; }

    const float sc = 1.0f / 2048.0f;
    #pragma unroll
    for (int ii = 0; ii < 4; ii++) {
        int i = t + ii * 256;
        float2 z0 = src[IX(2 * i)], z1 = src[IX(2 * i + 1)];
        ((float4*)xp)[i] = make_float4(z0.x * sc, z0.y * sc, z1.x * sc, z1.y * sc);
    }
}

// ---------------- K9: transpose back to (B,N,D) ----------------
__global__ __launch_bounds__(256) void k_transout(const float* __restrict__ xt,
                                                  float* __restrict__ out) {
    __shared__ float tile[64 * 65];
    int bid = blockIdx.x;
    int b = bid >> 10;
    int rem = bid & 1023;
    int nt = rem >> 4;
    int dt = rem & 15;
    int n0 = nt << 6;
    int tx = threadIdx.x & 63, ty = threadIdx.x >> 6;
    const float* xtb = xt + (((size_t)b * H_ + dt) * HD_) * (size_t)N_ + n0;
    for (int r = 0; r < 16; r++) {
        int dloc = ty + 4 * r;
        tile[dloc * 65 + tx] = xtb[(size_t)dloc * N_ + tx];
    }
    __syncthreads();
    float* ob = out + ((size_t)b * N_ + n0) * D_ + dt * HD_;
    for (int r = 0; r < 16; r++) {
        int nn = ty + 4 * r;
        ob[(size_t)nn * D_ + tx] = tile[tx * 65 + nn];
    }
}

extern "C" void kernel_launch(void* const* d_in, const int* in_sizes, int n_in,
                              void* d_out, int out_size, void* d_ws, size_t ws_size,
                              hipStream_t stream) {
    const float* x     = (const float*)d_in[0];
    const float* lnw   = (const float*)d_in[1];
    const float* lnb   = (const float*)d_in[2];
    const float* bfilt = (const float*)d_in[3];
    const float* bbias = (const float*)d_in[4];
    const float* w0    = (const float*)d_in[5];
    const float* b0    = (const float*)d_in[6];
    const float* w1    = (const float*)d_in[7];
    const float* b1    = (const float*)d_in[8];
    const float* w2    = (const float*)d_in[9];
    const float* b2    = (const float*)d_in[10];

    float* ws = (float*)d_ws;
    float*  xt    = ws;                                   // 16,777,216 floats
    float2* stats = (float2*)(ws + 16777216);             // 16384 float2
    float*  cpart = ws + 16777216 + 32768;                // 262,144
    float*  ctx   = cpart + 262144;                       // 4096
    float*  pA    = ctx + 4096;                           // 16384
    float*  pB    = pA + 16384;                           // 16384
    float*  p3    = pB + 16384;                           // 2,098,176
    float2* eff   = (float2*)(p3 + 2098176);              // 131,136 float2
    float*  out   = (float*)d_out;

    k_rowstats  <<<16384, 256, 0, stream>>>(x, stats);
    k_transnorm <<<4096,  256, 0, stream>>>(x, stats, lnw, lnb, xt, cpart);
    k_ctx       <<<16,    256, 0, stream>>>(cpart, ctx);
    k_mlp_part  <<<dim3(16, 4), 256, 0, stream>>>(ctx, w0, pA);
    k_mlp_part2 <<<dim3(16, 4), 256, 0, stream>>>(pA, b0, w1, pB);
    k_adapt_part<<<dim3(65, 8), 256, 0, stream>>>(pB, b1, w2, p3);
    k_eff       <<<129,   256, 0, stream>>>(p3, b2, bfilt, bbias, eff);
    k_fftmod    <<<4096,  256, 0, stream>>>(xt, eff);
    k_transout  <<<4096,  256, 0, stream>>>(xt, out);
}

// Round 3
// 240.141 us; speedup vs baseline: 1.3657x; 1.0290x over previous
//
#include <hip/hip_runtime.h>
#include <math.h>

#define B_ 4
#define N_ 4096
#define D_ 1024
#define H_ 16
#define HD_ 64
#define FB_ 2049

__device__ __forceinline__ float2 cmul(float2 a, float2 b) {
    return make_float2(a.x*b.x - a.y*b.y, a.x*b.y + a.y*b.x);
}
__device__ __forceinline__ float2 cadd(float2 a, float2 b){return make_float2(a.x+b.x,a.y+b.y);}
__device__ __forceinline__ float2 csub(float2 a, float2 b){return make_float2(a.x-b.x,a.y-b.y);}
__device__ __forceinline__ float2 cconj(float2 a){return make_float2(a.x,-a.y);}
// a + i*b  and  a - i*b
__device__ __forceinline__ float2 addi(float2 a, float2 b){return make_float2(a.x-b.y, a.y+b.x);}
__device__ __forceinline__ float2 subi(float2 a, float2 b){return make_float2(a.x+b.y, a.y-b.x);}

// tanh-approx GELU (jax.nn.gelu default), m >= 0 here
__device__ __forceinline__ float gelu_t(float m) {
    float u = 0.7978845608028654f * (m + 0.044715f * m * m * m);
    float e = __expf(-2.0f * u);
    float th = (1.0f - e) / (1.0f + e);
    return 0.5f * m * (1.0f + th);
}
__device__ __forceinline__ float2 cact(float2 z) {
    float m = sqrtf(z.x*z.x + z.y*z.y);
    float s = gelu_t(m) / (m + 1e-6f);
    return make_float2(z.x*s, z.y*s);
}

// skewed LDS index: breaks power-of-2 stride bank conflicts
#define IX(e) ((e) + ((e) >> 4))

// ---------------- K1: per-row LayerNorm stats ----------------
__global__ __launch_bounds__(256) void k_rowstats(const float* __restrict__ x,
                                                  float2* __restrict__ stats) {
    int row = blockIdx.x;
    const float4* xr = (const float4*)(x + (size_t)row * D_);
    float4 v = xr[threadIdx.x];
    float s = v.x + v.y + v.z + v.w;
    float q = v.x*v.x + v.y*v.y + v.z*v.z + v.w*v.w;
    for (int o = 32; o; o >>= 1) { s += __shfl_down(s, o); q += __shfl_down(q, o); }
    __shared__ float ls[4], lq[4];
    int lane = threadIdx.x & 63, w = threadIdx.x >> 6;
    if (!lane) { ls[w] = s; lq[w] = q; }
    __syncthreads();
    if (threadIdx.x == 0) {
        s = ls[0] + ls[1] + ls[2] + ls[3];
        q = lq[0] + lq[1] + lq[2] + lq[3];
        float mu = s * (1.0f / D_);
        float var = q * (1.0f / D_) - mu * mu;
        stats[row] = make_float2(mu, rsqrtf(var + 1e-5f));
    }
}

// ---------------- K2: LN apply + transpose to (b,h,d,n) + context partials ----------------
__global__ __launch_bounds__(256) void k_transnorm(const float* __restrict__ x,
                                                   const float2* __restrict__ stats,
                                                   const float* __restrict__ lnw,
                                                   const float* __restrict__ lnb,
                                                   float* __restrict__ xt,
                                                   float* __restrict__ cpart) {
    __shared__ float tile[64 * 65];
    __shared__ float gsum[256];
    int bid = blockIdx.x;
    int b = bid >> 10;
    int rem = bid & 1023;
    int nt = rem >> 4;
    int dt = rem & 15;
    int n0 = nt << 6, d0 = dt << 6;
    int tx = threadIdx.x & 63;
    int ty = threadIdx.x >> 6;
    float wv = lnw[d0 + tx], bv = lnb[d0 + tx];
    const float* xb = x + ((size_t)b * N_ + n0) * D_ + d0 + tx;
    for (int r = 0; r < 16; r++) {
        int row = ty + 4 * r;
        float2 st = stats[(size_t)b * N_ + n0 + row];
        float val = (xb[(size_t)row * D_] - st.x) * st.y * wv + bv;
        tile[row * 65 + tx] = val;
    }
    __syncthreads();
    float s = 0.f;
    for (int r = 0; r < 16; r++) s += tile[(ty * 16 + r) * 65 + tx];
    gsum[ty * 64 + tx] = s;
    float* xtb = xt + (((size_t)b * H_ + dt) * HD_) * (size_t)N_ + n0;
    for (int r = 0; r < 16; r++) {
        int dloc = ty + 4 * r;
        xtb[(size_t)dloc * N_ + tx] = tile[tx * 65 + dloc];
    }
    __syncthreads();
    if (threadIdx.x < 64) {
        float cs = gsum[threadIdx.x] + gsum[64 + threadIdx.x] +
                   gsum[128 + threadIdx.x] + gsum[192 + threadIdx.x];
        cpart[((size_t)b * 64 + nt) * D_ + d0 + threadIdx.x] = cs;
    }
}

// ---------------- K3: finalize context ----------------
__global__ __launch_bounds__(256) void k_ctx(const float* __restrict__ cpart,
                                             float* __restrict__ ctx) {
    int id = blockIdx.x * 256 + threadIdx.x;
    int b = id >> 10, d = id & 1023;
    float s = 0.f;
    const float* p = cpart + (size_t)b * 64 * D_ + d;
    #pragma unroll 8
    for (int g = 0; g < 64; g++) s += p[g * D_];
    ctx[id] = s * (1.0f / N_);
}

// ---------------- K4: layer-0 partial GEMM ----------------
__global__ __launch_bounds__(256) void k_mlp_part(const float* __restrict__ in,
                                                  const float* __restrict__ w,
                                                  float* __restrict__ part) {
    __shared__ float li[4 * 256];
    int ks = blockIdx.y;
    for (int i = threadIdx.x; i < 1024; i += 256) {
        int b = i >> 8, kk = i & 255;
        li[i] = in[b * 1024 + ks * 256 + kk];
    }
    __syncthreads();
    int col = blockIdx.x * 64 + (threadIdx.x & 63);
    int b = threadIdx.x >> 6;
    const float* wp = w + (size_t)(ks * 256) * 1024 + col;
    const float* ip = li + b * 256;
    float acc = 0.f;
    #pragma unroll 8
    for (int k = 0; k < 256; k++) acc = fmaf(ip[k], wp[(size_t)k * 1024], acc);
    part[((size_t)ks * 4 + b) * 1024 + col] = acc;
}

// ---------------- K5: layer-1 partial GEMM ----------------
__global__ __launch_bounds__(256) void k_mlp_part2(const float* __restrict__ part,
                                                   const float* __restrict__ bias,
                                                   const float* __restrict__ w,
                                                   float* __restrict__ part2) {
    __shared__ float li[4 * 256];
    int ks = blockIdx.y;
    for (int i = threadIdx.x; i < 1024; i += 256) {
        int b = i >> 8, kk = (i & 255) + ks * 256;
        float v = part[b * 1024 + kk] + part[4096 + b * 1024 + kk] +
                  part[8192 + b * 1024 + kk] + part[12288 + b * 1024 + kk] + bias[kk];
        li[i] = fmaxf(v, 0.f);
    }
    __syncthreads();
    int col = blockIdx.x * 64 + (threadIdx.x & 63);
    int b = threadIdx.x >> 6;
    const float* wp = w + (size_t)(ks * 256) * 1024 + col;
    const float* ip = li + b * 256;
    float acc = 0.f;
    #pragma unroll 8
    for (int k = 0; k < 256; k++) acc = fmaf(ip[k], wp[(size_t)k * 1024], acc);
    part2[((size_t)ks * 4 + b) * 1024 + col] = acc;
}

// ---------------- K6: w2 partial GEMM ----------------
__global__ __launch_bounds__(256) void k_adapt_part(const float* __restrict__ part2,
                                                    const float* __restrict__ b1,
                                                    const float* __restrict__ w2,
                                                    float* __restrict__ part3) {
    __shared__ float lh[4 * 128];
    int ks = blockIdx.y;
    for (int i = threadIdx.x; i < 512; i += 256) {
        int b = i >> 7, kk = (i & 127) + ks * 128;
        float v = part2[b * 1024 + kk] + part2[4096 + b * 1024 + kk] +
                  part2[8192 + b * 1024 + kk] + part2[12288 + b * 1024 + kk] + b1[kk];
        lh[i] = fmaxf(v, 0.f);
    }
    __syncthreads();
    int j4 = blockIdx.x * 1024 + threadIdx.x * 4;
    if (j4 < 65568) {
        float a0x=0,a0y=0,a0z=0,a0w=0, a1x=0,a1y=0,a1z=0,a1w=0;
        float a2x=0,a2y=0,a2z=0,a2w=0, a3x=0,a3y=0,a3z=0,a3w=0;
        const float* wp = w2 + (size_t)(ks * 128) * 65568 + j4;
        #pragma unroll 4
        for (int k = 0; k < 128; k++) {
            float4 wv = *(const float4*)(wp + (size_t)k * 65568);
            float h0 = lh[k], h1 = lh[128 + k], h2 = lh[256 + k], h3 = lh[384 + k];
            a0x = fmaf(h0, wv.x, a0x); a0y = fmaf(h0, wv.y, a0y);
            a0z = fmaf(h0, wv.z, a0z); a0w = fmaf(h0, wv.w, a0w);
            a1x = fmaf(h1, wv.x, a1x); a1y = fmaf(h1, wv.y, a1y);
            a1z = fmaf(h1, wv.z, a1z); a1w = fmaf(h1, wv.w, a1w);
            a2x = fmaf(h2, wv.x, a2x); a2y = fmaf(h2, wv.y, a2y);
            a2z = fmaf(h2, wv.z, a2z); a2w = fmaf(h2, wv.w, a2w);
            a3x = fmaf(h3, wv.x, a3x); a3y = fmaf(h3, wv.y, a3y);
            a3z = fmaf(h3, wv.z, a3z); a3w = fmaf(h3, wv.w, a3w);
        }
        float* p3 = part3 + (size_t)ks * 4 * 65568 + j4;
        *(float4*)(p3)              = make_float4(a0x, a0y, a0z, a0w);
        *(float4*)(p3 + 65568)      = make_float4(a1x, a1y, a1z, a1w);
        *(float4*)(p3 + 2 * 65568)  = make_float4(a2x, a2y, a2z, a2w);
        *(float4*)(p3 + 3 * 65568)  = make_float4(a3x, a3y, a3z, a3w);
    }
}

// ---------------- K7: finalize adapt -> effective filter/bias ----------------
__global__ __launch_bounds__(256) void k_eff(const float* __restrict__ part3,
                                             const float* __restrict__ b2,
                                             const float* __restrict__ bfilt,
                                             const float* __restrict__ bbias,
                                             float2* __restrict__ eff) {
    int p = blockIdx.x * 256 + threadIdx.x;     // 32784 = H*FB
    if (p >= 32784) return;
    int h = p / 2049, f = p % 2049;
    float bf = bfilt[p], bb = bbias[p];
    float sc0 = b2[2 * p], bi0 = b2[2 * p + 1];
    #pragma unroll
    for (int b = 0; b < 4; b++) {
        float sc = sc0, bi = bi0;
        #pragma unroll
        for (int s = 0; s < 8; s++) {
            const float* q = part3 + ((size_t)s * 4 + b) * 65568 + 2 * p;
            sc += q[0]; bi += q[1];
        }
        eff[((size_t)b * H_ + h) * FB_ + f] = make_float2(bf * (1.0f + sc), bb + bi);
    }
}

// ---------------- K8: two real signals per block, 4096-pt radix-8 FFT, mod, iFFT ---------
__global__ __launch_bounds__(512) void k_fftmod(float* __restrict__ xt,
                                                const float2* __restrict__ eff) {
    __shared__ float2 bufA[4352];
    __shared__ float2 bufB[4352];
    __shared__ float2 tw[1088];                 // e^{-2 pi i j/4096}, j<1024, skewed
    const float s2 = 0.70710678118654752f;
    int t = threadIdx.x;
    int sig0 = blockIdx.x * 2;                  // 2048 blocks, 2 signals each (same head)
    int b = sig0 >> 10;
    int h = (sig0 >> 6) & 15;
    const float2* ef = eff + ((size_t)b * H_ + h) * FB_;
    float* xa = xt + (size_t)sig0 * N_;
    float* xb = xa + N_;

    #pragma unroll
    for (int ii = 0; ii < 2; ii++) {
        int ji = t + ii * 512;
        float sv, cv;
        __sincosf(-(float)M_PI * (float)ji * (1.0f / 2048.0f), &sv, &cv);
        tw[IX(ji)] = make_float2(cv, sv);
    }
    #pragma unroll
    for (int ii = 0; ii < 2; ii++) {            // interleave two real signals as complex
        int i = t + ii * 512;
        float4 va = ((const float4*)xa)[i];
        float4 vb = ((const float4*)xb)[i];
        bufA[IX(4*i)]   = make_float2(va.x, vb.x);
        bufA[IX(4*i+1)] = make_float2(va.y, vb.y);
        bufA[IX(4*i+2)] = make_float2(va.z, vb.z);
        bufA[IX(4*i+3)] = make_float2(va.w, vb.w);
    }
    __syncthreads();

    float2 *src = bufA, *dst = bufB;
    // forward: 4 radix-8 stages (m = 1,8,64,512)
    for (int m = 1; m <= 512; m <<= 3) {
        int idx = t;
        int km = idx & (m - 1);
        int jm = idx - km;
        float2 u0 = src[IX(idx)];
        float2 u1 = src[IX(idx + 512)];
        float2 u2 = src[IX(idx + 1024)];
        float2 u3 = src[IX(idx + 1536)];
        float2 u4 = src[IX(idx + 2048)];
        float2 u5 = src[IX(idx + 2560)];
        float2 u6 = src[IX(idx + 3072)];
        float2 u7 = src[IX(idx + 3584)];
        float2 a0 = cadd(u0,u4), a1 = csub(u0,u4), a2 = cadd(u2,u6), a3 = csub(u2,u6);
        float2 E0 = cadd(a0,a2), E1 = subi(a1,a3), E2 = csub(a0,a2), E3 = addi(a1,a3);
        float2 c0 = cadd(u1,u5), c1 = csub(u1,u5), c2 = cadd(u3,u7), c3 = csub(u3,u7);
        float2 O0 = cadd(c0,c2), O1 = subi(c1,c3), O2 = csub(c0,c2), O3 = addi(c1,c3);
        float2 R1 = make_float2(s2*(O1.x + O1.y), s2*(O1.y - O1.x));
        float2 R2 = make_float2(O2.y, -O2.x);
        float2 R3 = make_float2(s2*(O3.y - O3.x), -s2*(O3.x + O3.y));
        float2 X0 = cadd(E0,O0), X4 = csub(E0,O0);
        float2 X1 = cadd(E1,R1), X5 = csub(E1,R1);
        float2 X2 = cadd(E2,R2), X6 = csub(E2,R2);
        float2 X3 = cadd(E3,R3), X7 = csub(E3,R3);
        float2 w1 = tw[IX(jm)];
        float2 w2 = cmul(w1,w1), w3 = cmul(w2,w1), w4 = cmul(w2,w2);
        float2 w5 = cmul(w4,w1), w6 = cmul(w4,w2), w7 = cmul(w4,w3);
        int base = 8*idx - 7*km;
        dst[IX(base)]       = X0;
        dst[IX(base + m)]   = cmul(w1,X1);
        dst[IX(base + 2*m)] = cmul(w2,X2);
        dst[IX(base + 3*m)] = cmul(w3,X3);
        dst[IX(base + 4*m)] = cmul(w4,X4);
        dst[IX(base + 5*m)] = cmul(w5,X5);
        dst[IX(base + 6*m)] = cmul(w6,X6);
        dst[IX(base + 7*m)] = cmul(w7,X7);
        __syncthreads();
        float2* tmp = src; src = dst; dst = tmp;
    }

    // spectral: separate two real spectra, modify+activate, recombine
    if (t == 0) {                                // k = 0
        float2 Z = src[IX(0)];
        float2 e0 = ef[0];
        float Av = Z.x * e0.x + e0.y;
        float Bv = Z.y * e0.x + e0.y;
        float ma = fabsf(Av); Av *= gelu_t(ma) / (ma + 1e-6f);
        float mb = fabsf(Bv); Bv *= gelu_t(mb) / (mb + 1e-6f);
        dst[IX(0)] = make_float2(Av, Bv);
    }
    #pragma unroll
    for (int ii = 0; ii < 4; ii++) {
        int k = 1 + t + ii * 512;                // 1..2048
        if (k == 2048) {                         // Nyquist (self-paired)
            float2 Z = src[IX(2048)];
            float2 eN = ef[2048];
            float Av = Z.x * eN.x + eN.y;
            float Bv = Z.y * eN.x + eN.y;
            float ma = fabsf(Av); Av *= gelu_t(ma) / (ma + 1e-6f);
            float mb = fabsf(Bv); Bv *= gelu_t(mb) / (mb + 1e-6f);
            dst[IX(2048)] = make_float2(Av, Bv);
        } else {
            float2 Zk = src[IX(k)], Zq = src[IX(4096 - k)];
            float2 A  = make_float2(0.5f*(Zk.x + Zq.x), 0.5f*(Zk.y - Zq.y));
            float2 Bc = make_float2(0.5f*(Zk.y + Zq.y), 0.5f*(Zq.x - Zk.x));
            float2 e = ef[k];
            float2 Ap = make_float2(A.x * e.x + e.y,  A.y * e.x);
            float2 Bp = make_float2(Bc.x * e.x + e.y, Bc.y * e.x);
            Ap = cact(Ap); Bp = cact(Bp);
            dst[IX(k)]        = make_float2(Ap.x - Bp.y, Ap.y + Bp.x);
            dst[IX(4096 - k)] = make_float2(Ap.x + Bp.y, Bp.x - Ap.y);
        }
    }
    __syncthreads();
    { float2* tmp = src; src = dst; dst = tmp; }

    // inverse: 4 radix-8 stages (conjugated)
    for (int m = 1; m <= 512; m <<= 3) {
        int idx = t;
        int km = idx & (m - 1);
        int jm = idx - km;
        float2 u0 = src[IX(idx)];
        float2 u1 = src[IX(idx + 512)];
        float2 u2 = src[IX(idx + 1024)];
        float2 u3 = src[IX(idx + 1536)];
        float2 u4 = src[IX(idx + 2048)];
        float2 u5 = src[IX(idx + 2560)];
        float2 u6 = src[IX(idx + 3072)];
        float2 u7 = src[IX(idx + 3584)];
        float2 a0 = cadd(u0,u4), a1 = csub(u0,u4), a2 = cadd(u2,u6), a3 = csub(u2,u6);
        float2 E0 = cadd(a0,a2), E1 = addi(a1,a3), E2 = csub(a0,a2), E3 = subi(a1,a3);
        float2 c0 = cadd(u1,u5), c1 = csub(u1,u5), c2 = cadd(u3,u7), c3 = csub(u3,u7);
        float2 O0 = cadd(c0,c2), O1 = addi(c1,c3), O2 = csub(c0,c2), O3 = subi(c1,c3);
        float2 R1 = make_float2(s2*(O1.x - O1.y),  s2*(O1.x + O1.y));
        float2 R2 = make_float2(-O2.y, O2.x);
        float2 R3 = make_float2(-s2*(O3.x + O3.y), s2*(O3.x - O3.y));
        float2 X0 = cadd(E0,O0), X4 = csub(E0,O0);
        float2 X1 = cadd(E1,R1), X5 = csub(E1,R1);
        float2 X2 = cadd(E2,R2), X6 = csub(E2,R2);
        float2 X3 = cadd(E3,R3), X7 = csub(E3,R3);
        float2 w1 = cconj(tw[IX(jm)]);
        float2 w2 = cmul(w1,w1), w3 = cmul(w2,w1), w4 = cmul(w2,w2);
        float2 w5 = cmul(w4,w1), w6 = cmul(w4,w2), w7 = cmul(w4,w3);
        int base = 8*idx - 7*km;
        dst[IX(base)]       = X0;
        dst[IX(base + m)]   = cmul(w1,X1);
        dst[IX(base + 2*m)] = cmul(w2,X2);
        dst[IX(base + 3*m)] = cmul(w3,X3);
        dst[IX(base + 4*m)] = cmul(w4,X4);
        dst[IX(base + 5*m)] = cmul(w5,X5);
        dst[IX(base + 6*m)] = cmul(w6,X6);
        dst[IX(base + 7*m)] = cmul(w7,X7);
        __syncthreads();
        float2* tmp = src; src = dst; dst = tmp;
    }

    const float sc = 1.0f / 4096.0f;
    #pragma unroll
    for (int ii = 0; ii < 2; ii++) {
        int i = t + ii * 512;
        float2 z0 = src[IX(4*i)],   z1 = src[IX(4*i+1)];
        float2 z2 = src[IX(4*i+2)], z3 = src[IX(4*i+3)];
        ((float4*)xa)[i] = make_float4(z0.x*sc, z1.x*sc, z2.x*sc, z3.x*sc);
        ((float4*)xb)[i] = make_float4(z0.y*sc, z1.y*sc, z2.y*sc, z3.y*sc);
    }
}

// ---------------- K9: transpose back to (B,N,D) ----------------
__global__ __launch_bounds__(256) void k_transout(const float* __restrict__ xt,
                                                  float* __restrict__ out) {
    __shared__ float tile[64 * 65];
    int bid = blockIdx.x;
    int b = bid >> 10;
    int rem = bid & 1023;
    int nt = rem >> 4;
    int dt = rem & 15;
    int n0 = nt << 6;
    int tx = threadIdx.x & 63, ty = threadIdx.x >> 6;
    const float* xtb = xt + (((size_t)b * H_ + dt) * HD_) * (size_t)N_ + n0;
    for (int r = 0; r < 16; r++) {
        int dloc = ty + 4 * r;
        tile[dloc * 65 + tx] = xtb[(size_t)dloc * N_ + tx];
    }
    __syncthreads();
    float* ob = out + ((size_t)b * N_ + n0) * D_ + dt * HD_;
    for (int r = 0; r < 16; r++) {
        int nn = ty + 4 * r;
        ob[(size_t)nn * D_ + tx] = tile[tx * 65 + nn];
    }
}

extern "C" void kernel_launch(void* const* d_in, const int* in_sizes, int n_in,
                              void* d_out, int out_size, void* d_ws, size_t ws_size,
                              hipStream_t stream) {
    const float* x     = (const float*)d_in[0];
    const float* lnw   = (const float*)d_in[1];
    const float* lnb   = (const float*)d_in[2];
    const float* bfilt = (const float*)d_in[3];
    const float* bbias = (const float*)d_in[4];
    const float* w0    = (const float*)d_in[5];
    const float* b0    = (const float*)d_in[6];
    const float* w1    = (const float*)d_in[7];
    const float* b1    = (const float*)d_in[8];
    const float* w2    = (const float*)d_in[9];
    const float* b2    = (const float*)d_in[10];

    float* ws = (float*)d_ws;
    float*  xt    = ws;                                   // 16,777,216 floats
    float2* stats = (float2*)(ws + 16777216);             // 16384 float2
    float*  cpart = ws + 16777216 + 32768;                // 262,144
    float*  ctx   = cpart + 262144;                       // 4096
    float*  pA    = ctx + 4096;                           // 16384
    float*  pB    = pA + 16384;                           // 16384
    float*  p3    = pB + 16384;                           // 2,098,176
    float2* eff   = (float2*)(p3 + 2098176);              // 131,136 float2
    float*  out   = (float*)d_out;

    k_rowstats  <<<16384, 256, 0, stream>>>(x, stats);
    k_transnorm <<<4096,  256, 0, stream>>>(x, stats, lnw, lnb, xt, cpart);
    k_ctx       <<<16,    256, 0, stream>>>(cpart, ctx);
    k_mlp_part  <<<dim3(16, 4), 256, 0, stream>>>(ctx, w0, pA);
    k_mlp_part2 <<<dim3(16, 4), 256, 0, stream>>>(pA, b0, w1, pB);
    k_adapt_part<<<dim3(65, 8), 256, 0, stream>>>(pB, b1, w2, p3);
    k_eff       <<<129,   256, 0, stream>>>(p3, b2, bfilt, bbias, eff);
    k_fftmod    <<<2048,  512, 0, stream>>>(xt, eff);
    k_transout  <<<4096,  256, 0, stream>>>(xt, out);
}